// Round 16
// baseline (159.179 us; speedup 1.0000x reference)
//
#include <hip/hip_runtime.h>
#include <math.h>

#define BATCHN 2
#define SEQ 2048
#define DMODEL 2048
#define NH 32
#define NKV 8
#define HDIM 64
#define KVD 512          // NKV*HDIM
#define ROWS 4096        // BATCHN*SEQ

typedef __bf16 bf16x8 __attribute__((ext_vector_type(8)));
typedef float f32x4 __attribute__((ext_vector_type(4)));
typedef unsigned short u16x8 __attribute__((ext_vector_type(8)));

#define MFMA(a, b, c) __builtin_amdgcn_mfma_f32_16x16x32_bf16(a, b, c, 0, 0, 0)

__device__ __forceinline__ unsigned short f2bf(float f) {
  union { float f; unsigned u; } v; v.f = f;
  unsigned u = v.u;
  u += 0x7fffu + ((u >> 16) & 1u);   // RNE
  return (unsigned short)(u >> 16);
}

__device__ __forceinline__ unsigned cvtpk(float a, float b) {
  unsigned r;
  asm("v_cvt_pk_bf16_f32 %0, %1, %2" : "=v"(r) : "v"(a), "v"(b));
  return r;
}
__device__ __forceinline__ void pl32(unsigned& a, unsigned& b) {
  asm("v_permlane32_swap_b32 %0, %1" : "+v"(a), "+v"(b));
}
__device__ __forceinline__ void pl16(unsigned& a, unsigned& b) {
  asm("v_permlane16_swap_b32 %0, %1" : "+v"(a), "+v"(b));
}
__device__ __forceinline__ float exp2v(float x) {
  float r;
  asm("v_exp_f32 %0, %1" : "=v"(r) : "v"(x));
  return r;
}

// async global->LDS, 16B per lane; LDS dest = wave-uniform base + lane*16 (HW rule)
__device__ __forceinline__ void gload16(const void* g, void* l) {
  __builtin_amdgcn_global_load_lds((const __attribute__((address_space(1))) unsigned int*)g,
                                   (__attribute__((address_space(3))) unsigned int*)l, 16, 0, 0);
}

#define FENCE() asm volatile("" ::: "memory")
#define BARRIER() do { FENCE(); __builtin_amdgcn_s_barrier(); FENCE(); } while (0)
#define VMCNT(n) asm volatile("s_waitcnt vmcnt(" #n ")" ::: "memory")

// ---------------- fused fp32->bf16 conversions + RoPE tables (one launch) ----------------
__global__ __launch_bounds__(256) void conv_all(const float* __restrict__ x,
                                                const float* __restrict__ Wq,
                                                const float* __restrict__ Wk,
                                                const float* __restrict__ Wv,
                                                const float* __restrict__ Wo,
                                                unsigned short* __restrict__ xb,
                                                unsigned short* __restrict__ Wqb,
                                                unsigned short* __restrict__ Wkb,
                                                unsigned short* __restrict__ Wvb,
                                                unsigned short* __restrict__ Wob,
                                                float* __restrict__ ct,
                                                float* __restrict__ st) {
  int i = blockIdx.x * 256 + threadIdx.x;
  const float* in;
  unsigned short* out;
  int off;
  if (i < 2097152)      { in = x;  out = xb;  off = i; }
  else if (i < 3145728) { in = Wq; out = Wqb; off = i - 2097152; }
  else if (i < 3407872) { in = Wk; out = Wkb; off = i - 3145728; }
  else if (i < 3670016) { in = Wv; out = Wvb; off = i - 3407872; }
  else if (i < 4718592) { in = Wo; out = Wob; off = i - 3670016; }
  else {
    int t = i - 4718592;  // 0..65535 : RoPE tables [SEQ][32]
    int s = t >> 5, f = t & 31;
    float inv = __expf(-(float)f * (9.210340371976184f / 32.0f));  // 10000^(-f/32)
    float ang = (float)s * inv;
    ct[t] = cosf(ang);
    st[t] = sinf(ang);
    return;
  }
  float4 v = ((const float4*)in)[off];
  ushort4 o;
  o.x = f2bf(v.x); o.y = f2bf(v.y); o.z = f2bf(v.z); o.w = f2bf(v.w);
  ((ushort4*)out)[off] = o;
}

// ================= QKV GEMM (two-phase): 128x384 tile, BK=64, 8 waves =================
// 256 blocks = 1/CU. XCD chunk now 4bm x 8grp (A footprint 2MB/XCD, L2-resident;
// B streams once via L3). bm-fastest within chunk preserves B-panel back-to-back reuse.
__global__ __launch_bounds__(512, 2) void gemm_qkv384(const unsigned short* __restrict__ A,
                                                      const unsigned short* __restrict__ Bq,
                                                      const unsigned short* __restrict__ Bk,
                                                      const unsigned short* __restrict__ Bv,
                                                      unsigned short* __restrict__ Qo,
                                                      unsigned short* __restrict__ Ko,
                                                      unsigned short* __restrict__ Vt,
                                                      const float* __restrict__ ct,
                                                      const float* __restrict__ st) {
  __shared__ __align__(16) unsigned short Als[3][8192];      // 48KB
  __shared__ __align__(16) unsigned short Bls[3][2][8192];   // 96KB [bank][buf]
  const int tid = threadIdx.x, lane = tid & 63, wv = tid >> 6;
  const int wm = wv >> 2, wn = wv & 3;
  const int g = lane >> 4, r15 = lane & 15;
  // 256 blocks; XCD chunk = 4bm x 8grp, bm-fastest
  const int c = blockIdx.x & 7, i = blockIdx.x >> 3;   // xcd, within (0..31)
  const int bm = c * 4 + (i & 3);                      // 0..31
  const int grp = i >> 2;                              // 0..7 (3 bn-panels each)
  const int row0 = bm << 7;
  const unsigned short* Bpan[3];
  int bnp[3];
#pragma unroll
  for (int bk = 0; bk < 3; ++bk) {
    int p = grp * 3 + bk;
    bnp[bk] = p;
    Bpan[bk] = (p < 16) ? Bq + (size_t)(p << 7) * DMODEL
             : (p < 20) ? Bk + (size_t)((p - 16) << 7) * DMODEL
                        : Bv + (size_t)((p - 20) << 7) * DMODEL;
  }
  const int srow = tid >> 3;                             // 0..63
  const int scol = (((tid & 7) ^ ((tid >> 3) & 7)) << 3);
  const unsigned short* gA = A + (size_t)(row0 + srow) * DMODEL + scol;
  const unsigned short* gB0 = Bpan[0] + (size_t)srow * DMODEL + scol;
  const unsigned short* gB1 = Bpan[1] + (size_t)srow * DMODEL + scol;
  const unsigned short* gB2 = Bpan[2] + (size_t)srow * DMODEL + scol;

  f32x4 acc[4][6];
#pragma unroll
  for (int a = 0; a < 4; ++a)
#pragma unroll
    for (int b = 0; b < 6; ++b) acc[a][b] = (f32x4){0.f, 0.f, 0.f, 0.f};

#define STG_A(buf, kt) do { \
    gload16(gA + (size_t)(kt) * 64, &Als[buf][(wv << 9)]); \
    gload16(gA + (size_t)64 * DMODEL + (size_t)(kt) * 64, &Als[buf][4096 + (wv << 9)]); } while (0)
#define STG_B(bank, gp, buf, kt) do { \
    gload16(gp + (size_t)(kt) * 64, &Bls[bank][buf][(wv << 9)]); \
    gload16(gp + (size_t)64 * DMODEL + (size_t)(kt) * 64, &Bls[bank][buf][4096 + (wv << 9)]); } while (0)
#define RA(buf, mf, kk) (*(const bf16x8*)&Als[buf][((wm << 6) + ((mf) << 4) + r15) * 64 + \
                          (((((kk) << 2) + g) ^ (r15 & 7)) << 3)])
#define RB(bank, buf, sub, kk) (*(const bf16x8*)&Bls[bank][buf][((wn << 5) + ((sub) << 4) + r15) * 64 + \
                          (((((kk) << 2) + g) ^ (r15 & 7)) << 3)])

  STG_A(0, 0);
  STG_B(0, gB0, 0, 0); STG_B(1, gB1, 0, 0); STG_B(2, gB2, 0, 0);
  STG_A(1, 1);
  VMCNT(0);
  BARRIER();

  const int NT = DMODEL / 64;  // 32
  for (int t = 0; t < NT; ++t) {
    const int ab = t % 3, an2 = (t + 2) % 3;
    const int bb = t & 1, bn2 = bb ^ 1;
    // ---- ph0: read A(8) + banks 0,1 (8); stage B(t+1) x3; MFMA 32 ----
    bf16x8 af[4][2];
#pragma unroll
    for (int mf = 0; mf < 4; ++mf) { af[mf][0] = RA(ab, mf, 0); af[mf][1] = RA(ab, mf, 1); }
    bf16x8 b01[2][2][2];
#pragma unroll
    for (int bk = 0; bk < 2; ++bk)
#pragma unroll
      for (int sub = 0; sub < 2; ++sub) {
        b01[bk][sub][0] = RB(bk, bb, sub, 0);
        b01[bk][sub][1] = RB(bk, bb, sub, 1);
      }
    if (t + 1 < NT) {
      STG_B(0, gB0, bn2, t + 1); STG_B(1, gB1, bn2, t + 1); STG_B(2, gB2, bn2, t + 1);
    }
    BARRIER();
    __builtin_amdgcn_s_setprio(1);
#pragma unroll
    for (int mf = 0; mf < 4; ++mf)
#pragma unroll
      for (int bk = 0; bk < 2; ++bk)
#pragma unroll
        for (int sub = 0; sub < 2; ++sub) {
          acc[mf][bk * 2 + sub] = MFMA(af[mf][0], b01[bk][sub][0], acc[mf][bk * 2 + sub]);
          acc[mf][bk * 2 + sub] = MFMA(af[mf][1], b01[bk][sub][1], acc[mf][bk * 2 + sub]);
        }
    __builtin_amdgcn_s_setprio(0);
    BARRIER();
    // ---- ph1: read bank 2 (4); stage A(t+2); MFMA 16; counted drain ----
    bf16x8 b2[2][2];
#pragma unroll
    for (int sub = 0; sub < 2; ++sub) { b2[sub][0] = RB(2, bb, sub, 0); b2[sub][1] = RB(2, bb, sub, 1); }
    if (t + 2 < NT) STG_A(an2, t + 2);
    BARRIER();
    __builtin_amdgcn_s_setprio(1);
#pragma unroll
    for (int mf = 0; mf < 4; ++mf)
#pragma unroll
      for (int sub = 0; sub < 2; ++sub) {
        acc[mf][4 + sub] = MFMA(af[mf][0], b2[sub][0], acc[mf][4 + sub]);
        acc[mf][4 + sub] = MFMA(af[mf][1], b2[sub][1], acc[mf][4 + sub]);
      }
    __builtin_amdgcn_s_setprio(0);
    if (t + 2 < NT)      { VMCNT(2); }
    else if (t + 1 < NT) { VMCNT(0); }
    BARRIER();
  }
#undef STG_A
#undef STG_B
#undef RA
#undef RB

  // ---- epilogue: per-bank Q / K / V(transposed) ----
  const float QS = 0.18033688011112042f;  // 0.125 * log2(e)
#pragma unroll
  for (int bk = 0; bk < 3; ++bk) {
    const int p = bnp[bk];
    if (p < 20) {
      unsigned short* Outb = (p < 16) ? Qo : Ko;
      const int col0 = (p < 16) ? (p << 7) : ((p - 16) << 7);
      const int ldo = (p < 16) ? DMODEL : KVD;
      const int qsc = (p < 16);
#pragma unroll
      for (int mf = 0; mf < 4; ++mf) {
#pragma unroll
        for (int rr = 0; rr < 4; ++rr) {
          const int m = row0 + (wm << 6) + (mf << 4) + (g << 2) + rr;
          const float* ctr = ct + ((m & (SEQ - 1)) << 5);
          const float* str = st + ((m & (SEQ - 1)) << 5);
#pragma unroll
          for (int sub = 0; sub < 2; ++sub) {
            const int n = col0 + (wn << 5) + (sub << 4) + r15;
            float v = acc[mf][bk * 2 + sub][rr];
            float pv = __shfl_xor(v, 1);
            int fi = (n & 63) >> 1;
            float cc = ctr[fi], sn = str[fi];
            v = (lane & 1) ? (pv * sn + v * cc) : (v * cc - pv * sn);
            if (qsc) v *= QS;
            Outb[(size_t)m * ldo + n] = f2bf(v);
          }
        }
      }
    } else {
      const int col0 = (p - 20) << 7;
#pragma unroll
      for (int mf = 0; mf < 4; ++mf) {
        const int m0 = row0 + (wm << 6) + (mf << 4) + (g << 2);
        const int b = m0 >> 11, s0 = m0 & (SEQ - 1);
#pragma unroll
        for (int sub = 0; sub < 2; ++sub) {
          const int nv = col0 + (wn << 5) + (sub << 4) + r15;  // 0..511 = kvh*64+d
          ushort4 o;
          o.x = f2bf(acc[mf][bk * 2 + sub][0]);
          o.y = f2bf(acc[mf][bk * 2 + sub][1]);
          o.z = f2bf(acc[mf][bk * 2 + sub][2]);
          o.w = f2bf(acc[mf][bk * 2 + sub][3]);
          *(ushort4*)(Vt + ((size_t)(b * NKV * HDIM + nv)) * SEQ + s0) = o;
        }
      }
    }
  }
}

// ================= out-proj GEMM: 128x256, BK=64, 8 waves, SINGLE merged phase, 3-buf =================
__global__ __launch_bounds__(512) void gemm_out128(const unsigned short* __restrict__ A,
                                                   const unsigned short* __restrict__ B,
                                                   float* __restrict__ C) {
  __shared__ __align__(16) unsigned short Als[3][8192];      // [buf][128*64]
  __shared__ __align__(16) unsigned short Bls[3][2][8192];   // [buf][half][128*64]
  const int tid = threadIdx.x, lane = tid & 63, wv = tid >> 6;
  const int wm = wv >> 2, wn = wv & 3;
  const int g = lane >> 4, r15 = lane & 15;
  const int wgid = (blockIdx.x & 7) * 32 + (blockIdx.x >> 3);
  const int bm = wgid >> 3, bn = wgid & 7;
  const int row0 = bm << 7, col0 = bn << 8;
  const int srl = tid >> 3;
  const int sgc = ((tid & 7) ^ (srl & 7)) << 3;
  const unsigned short* gA = A + (size_t)(row0 + srl) * DMODEL + sgc;
  const unsigned short* gB = B + (size_t)(col0 + srl) * DMODEL + sgc;

  f32x4 acc[4][4];
#pragma unroll
  for (int i = 0; i < 4; ++i)
#pragma unroll
    for (int jj = 0; jj < 4; ++jj) acc[i][jj] = (f32x4){0.f, 0.f, 0.f, 0.f};

#define STG_A1(buf, kt) do { \
    gload16(gA + (size_t)(kt) * 64, &Als[buf][(wv << 9)]); \
    gload16(gA + (size_t)64 * DMODEL + (size_t)(kt) * 64, &Als[buf][4096 + (wv << 9)]); } while (0)
#define STG_B1(buf, h, kt) do { \
    gload16(gB + (size_t)((h) * 128) * DMODEL + (kt) * 64, &Bls[buf][h][(wv << 9)]); \
    gload16(gB + (size_t)((h) * 128 + 64) * DMODEL + (kt) * 64, &Bls[buf][h][4096 + (wv << 9)]); } while (0)
#define RA1(buf, mf, kk) (*(const bf16x8*)&Als[buf][((wm << 6) + (mf) * 16 + r15) * 64 + \
                           (((((kk) << 2) + g) ^ (r15 & 7)) << 3)])
#define RB1(buf, nf, kk) (*(const bf16x8*)&Bls[buf][wn >> 1][((wn & 1) * 64 + (nf) * 16 + r15) * 64 + \
                           (((((kk) << 2) + g) ^ (r15 & 7)) << 3)])

  STG_B1(0, 0, 0); STG_B1(0, 1, 0); STG_A1(0, 0);
  STG_B1(1, 0, 1); STG_B1(1, 1, 1); STG_A1(1, 1);
  VMCNT(6);
  BARRIER();

  const int NT = DMODEL / 64;  // 32
  for (int t = 0; t < NT; ++t) {
    const int cur = t % 3;
    const int stg = (t + 2) % 3;
    bf16x8 a[4][2], b0[2][2], b2[2][2];
#pragma unroll
    for (int mf = 0; mf < 4; ++mf) { a[mf][0] = RA1(cur, mf, 0); a[mf][1] = RA1(cur, mf, 1); }
#pragma unroll
    for (int nf = 0; nf < 2; ++nf) { b0[nf][0] = RB1(cur, nf, 0); b0[nf][1] = RB1(cur, nf, 1); }
#pragma unroll
    for (int nf = 0; nf < 2; ++nf) { b2[nf][0] = RB1(cur, 2 + nf, 0); b2[nf][1] = RB1(cur, 2 + nf, 1); }
    if (t + 2 < NT) { STG_B1(stg, 0, t + 2); STG_B1(stg, 1, t + 2); STG_A1(stg, t + 2); }
    BARRIER();
    __builtin_amdgcn_s_setprio(1);
#pragma unroll
    for (int mf = 0; mf < 4; ++mf)
#pragma unroll
      for (int nf = 0; nf < 2; ++nf) {
        acc[mf][nf] = MFMA(a[mf][0], b0[nf][0], acc[mf][nf]);
        acc[mf][nf] = MFMA(a[mf][1], b0[nf][1], acc[mf][nf]);
        acc[mf][2 + nf] = MFMA(a[mf][0], b2[nf][0], acc[mf][2 + nf]);
        acc[mf][2 + nf] = MFMA(a[mf][1], b2[nf][1], acc[mf][2 + nf]);
      }
    __builtin_amdgcn_s_setprio(0);
    if (t + 2 < NT) { VMCNT(6); }
    else if (t + 2 == NT) { VMCNT(0); }
    BARRIER();
  }
#undef STG_A1
#undef STG_B1
#undef RA1
#undef RB1

#pragma unroll
  for (int mf = 0; mf < 4; ++mf)
#pragma unroll
    for (int rr = 0; rr < 4; ++rr) {
      const int m = row0 + (wm << 6) + (mf) * 16 + (g << 2) + rr;
#pragma unroll
      for (int nf = 0; nf < 4; ++nf)
        C[(size_t)m * DMODEL + col0 + (wn << 6) + (nf << 4) + r15] = acc[mf][nf][rr];
    }
}

// ---------------- Flash attention: 8-wave, QBLK=128, KVBLK=128, 2-half T15 pipeline ----------------
__global__ __launch_bounds__(512, 4) void attn_fwd(const unsigned short* __restrict__ Q,
                                                   const unsigned short* __restrict__ K,
                                                   const unsigned short* __restrict__ Vt,
                                                   unsigned short* __restrict__ O) {
  __shared__ __align__(16) unsigned short Kls[2][2][64 * 64];
  __shared__ __align__(16) unsigned short Vls[2][2][64 * 64];
  const int bid = blockIdx.x;
  const int xcd = bid & 7;
  const int within = bid >> 3;             // 0..63
  const int grp = xcd * 2 + (within >> 5); // 0..15 = (b,kvh)
  const int w32 = within & 31;
  const int j = w32 & 7;                   // pair: q-tiles j and 15-j (128 rows each)
  const int hsub = w32 >> 3;
  const int b = grp >> 3, kvh = grp & 7;
  const int h = kvh * 4 + hsub;
  const int wave = threadIdx.x >> 6, lane = threadIdx.x & 63;  // 8 waves
  const int g = lane >> 4, r15 = lane & 15;
  const int sr = lane >> 3;
  const int sc = (((lane & 7) << 4) ^ (sr << 4)) >> 1;  // pre-swizzled src col (shorts)
  const unsigned short* kbase = K + (size_t)b * SEQ * KVD + kvh * HDIM;
  const unsigned short* vbase = Vt + (size_t)((b * NKV + kvh) * HDIM) * SEQ;

  union { u16x8 s; bf16x8 v; } one8;
#pragma unroll
  for (int z = 0; z < 8; ++z) one8.s[z] = 0x3F80;  // bf16 1.0

  auto STAGE = [&](int bi, int kbv) {
    const int r = wave * 8;   // 8 rows per wave per subtile
#pragma unroll
    for (int hh = 0; hh < 2; ++hh) {
      gload16(kbase + (size_t)(kbv + hh * 64 + r + sr) * KVD + sc, &Kls[bi][hh][r * 64]);
      gload16(vbase + (size_t)(r + sr) * SEQ + kbv + hh * 64 + sc, &Vls[bi][hh][r * 64]);
    }
  };

#pragma unroll 1
  for (int sel = 0; sel < 2; ++sel) {
    const int qt = sel ? (15 - j) : j;
    const int qrow0 = qt * 128 + wave * 16;
    const unsigned short* qp = Q + (size_t)(b * SEQ + qrow0 + r15) * DMODEL + h * HDIM;
    bf16x8 q0 = *(const bf16x8*)(qp + g * 8);
    bf16x8 q1 = *(const bf16x8*)(qp + 32 + g * 8);
    f32x4 oacc[4] = {};
    f32x4 lacc = {};
    const int kend = (qt + 1) * 128;
    __syncthreads();           // prior-tile reads drained before restaging
    STAGE(0, 0);
    int buf = 0;
    for (int kb = 0; kb < kend; kb += 128) {
      __syncthreads();         // staged loads for buf complete; buf^1 reads done
      if (kb + 128 < kend) STAGE(buf ^ 1, kb + 128);
      const char* Kc0 = (const char*)&Kls[buf][0][0];
      const char* Vc0 = (const char*)&Vls[buf][0][0];
      const char* Kc1 = (const char*)&Kls[buf][1][0];
      const char* Vc1 = (const char*)&Vls[buf][1][0];
      // ---- QK^T for BOTH halves first ----
      f32x4 s0[4], s1[4];
      __builtin_amdgcn_s_setprio(1);
#pragma unroll
      for (int f = 0; f < 4; ++f) {
        const int r = f * 16 + r15;
        const int sw = (r & 7) << 4;
        bf16x8 k0 = *(const bf16x8*)(Kc0 + r * 128 + ((g * 16) ^ sw));
        bf16x8 k1 = *(const bf16x8*)(Kc0 + r * 128 + ((64 + g * 16) ^ sw));
        f32x4 z = {};
        s0[f] = MFMA(k1, q1, MFMA(k0, q0, z));
      }
#pragma unroll
      for (int f = 0; f < 4; ++f) {
        const int r = f * 16 + r15;
        const int sw = (r & 7) << 4;
        bf16x8 k0 = *(const bf16x8*)(Kc1 + r * 128 + ((g * 16) ^ sw));
        bf16x8 k1 = *(const bf16x8*)(Kc1 + r * 128 + ((64 + g * 16) ^ sw));
        f32x4 z = {};
        s1[f] = MFMA(k1, q1, MFMA(k0, q0, z));
      }
      __builtin_amdgcn_s_setprio(0);
      // ---- softmax(h0) ----
      if (kb + 64 > qrow0) {
        const int q = qrow0 + r15;
#pragma unroll
        for (int f = 0; f < 4; ++f)
#pragma unroll
          for (int rr = 0; rr < 4; ++rr)
            if (kb + f * 16 + g * 4 + rr > q) s0[f][rr] = -1e30f;
      }
#pragma unroll
      for (int f = 0; f < 4; ++f)
#pragma unroll
        for (int rr = 0; rr < 4; ++rr) s0[f][rr] = exp2v(s0[f][rr]);
      bf16x8 p1a, p2a;
      {
        union { bf16x8 v; unsigned u[4]; } P1, P2;
        unsigned a0 = cvtpk(s0[0][0], s0[0][1]), b0 = cvtpk(s0[1][0], s0[1][1]);
        pl32(a0, b0); pl16(a0, b0);
        unsigned a1 = cvtpk(s0[0][2], s0[0][3]), b1 = cvtpk(s0[1][2], s0[1][3]);
        pl32(a1, b1); pl16(a1, b1);
        P1.u[0] = a0; P1.u[1] = a1; P1.u[2] = b0; P1.u[3] = b1;
        unsigned a2 = cvtpk(s0[2][0], s0[2][1]), b2 = cvtpk(s0[3][0], s0[3][1]);
        pl32(a2, b2); pl16(a2, b2);
        unsigned a3 = cvtpk(s0[2][2], s0[2][3]), b3 = cvtpk(s0[3][2], s0[3][3]);
        pl32(a3, b3); pl16(a3, b3);
        P2.u[0] = a2; P2.u[1] = a3; P2.u[2] = b2; P2.u[3] = b3;
        p1a = P1.v; p2a = P2.v;
      }
      lacc = MFMA(p2a, one8.v, MFMA(p1a, one8.v, lacc));
      // ---- PV(h0) ----
      __builtin_amdgcn_s_setprio(1);
#pragma unroll
      for (int dc = 0; dc < 4; ++dc) {
        const int r = dc * 16 + r15;
        const int sw = (r & 7) << 4;
        bf16x8 v0 = *(const bf16x8*)(Vc0 + r * 128 + ((g * 16) ^ sw));
        bf16x8 v1 = *(const bf16x8*)(Vc0 + r * 128 + ((64 + g * 16) ^ sw));
        oacc[dc] = MFMA(p2a, v1, MFMA(p1a, v0, oacc[dc]));
      }
      __builtin_amdgcn_s_setprio(0);
      // ---- softmax(h1) (overlaps PV(h0)) ----
      const int cb1 = kb + 64;
      if (cb1 + 64 > qrow0) {
        const int q = qrow0 + r15;
#pragma unroll
        for (int f = 0; f < 4; ++f)
#pragma unroll
          for (int rr = 0; rr < 4; ++rr)
            if (cb1 + f * 16 + g * 4 + rr > q) s1[f][rr] = -1e30f;
      }
#pragma unroll
      for (int f = 0; f < 4; ++f)
#pragma unroll
        for (int rr = 0; rr < 4; ++rr) s1[f][rr] = exp2v(s1[f][rr]);
      bf16x8 p1b, p2b;
      {
        union { bf16x8 v; unsigned u[4]; } P1, P2;
        unsigned a0 = cvtpk(s1[0][0], s1[0][1]), b0 = cvtpk(s1[1][0], s1[1][1]);
        pl32(a0, b0); pl16(a0, b0);
        unsigned a1 = cvtpk(s1[0][2], s1[0][3]), b1 = cvtpk(s1[1][2], s1[1][3]);
        pl32(a1, b1); pl16(a1, b1);
        P1.u[0] = a0; P1.u[1] = a1; P1.u[2] = b0; P1.u[3] = b1;
        unsigned a2 = cvtpk(s1[2][0], s1[2][1]), b2 = cvtpk(s1[3][0], s1[3][1]);
        pl32(a2, b2); pl16(a2, b2);
        unsigned a3 = cvtpk(s1[2][2], s1[2][3]), b3 = cvtpk(s1[3][2], s1[3][3]);
        pl32(a3, b3); pl16(a3, b3);
        P2.u[0] = a2; P2.u[1] = a3; P2.u[2] = b2; P2.u[3] = b3;
        p1b = P1.v; p2b = P2.v;
      }
      lacc = MFMA(p2b, one8.v, MFMA(p1b, one8.v, lacc));
      // ---- PV(h1) ----
      __builtin_amdgcn_s_setprio(1);
#pragma unroll
      for (int dc = 0; dc < 4; ++dc) {
        const int r = dc * 16 + r15;
        const int sw = (r & 7) << 4;
        bf16x8 v0 = *(const bf16x8*)(Vc1 + r * 128 + ((g * 16) ^ sw));
        bf16x8 v1 = *(const bf16x8*)(Vc1 + r * 128 + ((64 + g * 16) ^ sw));
        oacc[dc] = MFMA(p2b, v1, MFMA(p1b, v0, oacc[dc]));
      }
      __builtin_amdgcn_s_setprio(0);
      buf ^= 1;
    }
    float rls[4];
#pragma unroll
    for (int rr = 0; rr < 4; ++rr) rls[rr] = 1.0f / lacc[rr];
    unsigned short* optr = O + (size_t)(b * SEQ + qrow0) * DMODEL + h * HDIM;
#pragma unroll
    for (int dc = 0; dc < 4; ++dc)
#pragma unroll
      for (int rr = 0; rr < 4; ++rr)
        optr[(size_t)(g * 4 + rr) * DMODEL + dc * 16 + r15] = f2bf(oacc[dc][rr] * rls[rr]);
  }
}

extern "C" void kernel_launch(void* const* d_in, const int* in_sizes, int n_in,
                              void* d_out, int out_size, void* d_ws, size_t ws_size,
                              hipStream_t stream) {
  const float* x  = (const float*)d_in[0];
  const float* Wq = (const float*)d_in[1];
  const float* Wk = (const float*)d_in[2];
  const float* Wv = (const float*)d_in[3];
  const float* Wo = (const float*)d_in[4];

  char* ws = (char*)d_ws;
  unsigned short* xb  = (unsigned short*)(ws);                    // 16 MiB
  unsigned short* Wqb = (unsigned short*)(ws + (16u << 20));      // 8 MiB
  unsigned short* Wkb = (unsigned short*)(ws + (24u << 20));      // 2 MiB
  unsigned short* Wvb = (unsigned short*)(ws + (26u << 20));      // 2 MiB
  unsigned short* Wob = (unsigned short*)(ws + (28u << 20));      // 8 MiB
  unsigned short* Qb  = (unsigned short*)(ws + (36u << 20));      // 16 MiB
  unsigned short* Kb  = (unsigned short*)(ws + (52u << 20));      // 4 MiB
  unsigned short* Vtb = (unsigned short*)(ws + (60u << 20));      // 4 MiB
  unsigned short* AO  = (unsigned short*)(ws + (64u << 20));      // 16 MiB
  float* ct = (float*)(ws + (80u << 20));                         // 256 KiB
  float* st = (float*)(ws + (81u << 20));                         // 256 KiB

  conv_all<<<18688, 256, 0, stream>>>(x, Wq, Wk, Wv, Wo, xb, Wqb, Wkb, Wvb, Wob, ct, st);

  gemm_qkv384<<<256, 512, 0, stream>>>(xb, Wqb, Wkb, Wvb, Qb, Kb, Vtb, ct, st);

  attn_fwd<<<512, 512, 0, stream>>>(Qb, Kb, Vtb, AO);

  gemm_out128<<<256, 512, 0, stream>>>(AO, Wob, (float*)d_out);
}

// Round 17
// 158.856 us; speedup vs baseline: 1.0020x; 1.0020x over previous
//
#include <hip/hip_runtime.h>
#include <math.h>

#define BATCHN 2
#define SEQ 2048
#define DMODEL 2048
#define NH 32
#define NKV 8
#define HDIM 64
#define KVD 512          // NKV*HDIM
#define ROWS 4096        // BATCHN*SEQ

typedef __bf16 bf16x8 __attribute__((ext_vector_type(8)));
typedef float f32x4 __attribute__((ext_vector_type(4)));
typedef unsigned short u16x8 __attribute__((ext_vector_type(8)));

#define MFMA(a, b, c) __builtin_amdgcn_mfma_f32_16x16x32_bf16(a, b, c, 0, 0, 0)

__device__ __forceinline__ unsigned short f2bf(float f) {
  union { float f; unsigned u; } v; v.f = f;
  unsigned u = v.u;
  u += 0x7fffu + ((u >> 16) & 1u);   // RNE
  return (unsigned short)(u >> 16);
}

__device__ __forceinline__ unsigned cvtpk(float a, float b) {
  unsigned r;
  asm("v_cvt_pk_bf16_f32 %0, %1, %2" : "=v"(r) : "v"(a), "v"(b));
  return r;
}
__device__ __forceinline__ void pl32(unsigned& a, unsigned& b) {
  asm("v_permlane32_swap_b32 %0, %1" : "+v"(a), "+v"(b));
}
__device__ __forceinline__ void pl16(unsigned& a, unsigned& b) {
  asm("v_permlane16_swap_b32 %0, %1" : "+v"(a), "+v"(b));
}
__device__ __forceinline__ float exp2v(float x) {
  float r;
  asm("v_exp_f32 %0, %1" : "=v"(r) : "v"(x));
  return r;
}

// async global->LDS, 16B per lane; LDS dest = wave-uniform base + lane*16 (HW rule)
__device__ __forceinline__ void gload16(const void* g, void* l) {
  __builtin_amdgcn_global_load_lds((const __attribute__((address_space(1))) unsigned int*)g,
                                   (__attribute__((address_space(3))) unsigned int*)l, 16, 0, 0);
}

#define FENCE() asm volatile("" ::: "memory")
#define BARRIER() do { FENCE(); __builtin_amdgcn_s_barrier(); FENCE(); } while (0)
#define VMCNT(n) asm volatile("s_waitcnt vmcnt(" #n ")" ::: "memory")

// ---------------- fused fp32->bf16 conversions + RoPE tables (one launch) ----------------
__global__ __launch_bounds__(256) void conv_all(const float* __restrict__ x,
                                                const float* __restrict__ Wq,
                                                const float* __restrict__ Wk,
                                                const float* __restrict__ Wv,
                                                const float* __restrict__ Wo,
                                                unsigned short* __restrict__ xb,
                                                unsigned short* __restrict__ Wqb,
                                                unsigned short* __restrict__ Wkb,
                                                unsigned short* __restrict__ Wvb,
                                                unsigned short* __restrict__ Wob,
                                                float* __restrict__ ct,
                                                float* __restrict__ st) {
  int i = blockIdx.x * 256 + threadIdx.x;
  const float* in;
  unsigned short* out;
  int off;
  if (i < 2097152)      { in = x;  out = xb;  off = i; }
  else if (i < 3145728) { in = Wq; out = Wqb; off = i - 2097152; }
  else if (i < 3407872) { in = Wk; out = Wkb; off = i - 3145728; }
  else if (i < 3670016) { in = Wv; out = Wvb; off = i - 3407872; }
  else if (i < 4718592) { in = Wo; out = Wob; off = i - 3670016; }
  else {
    int t = i - 4718592;  // 0..65535 : RoPE tables [SEQ][32]
    int s = t >> 5, f = t & 31;
    float inv = __expf(-(float)f * (9.210340371976184f / 32.0f));  // 10000^(-f/32)
    float ang = (float)s * inv;
    ct[t] = cosf(ang);
    st[t] = sinf(ang);
    return;
  }
  float4 v = ((const float4*)in)[off];
  ushort4 o;
  o.x = f2bf(v.x); o.y = f2bf(v.y); o.z = f2bf(v.z); o.w = f2bf(v.w);
  ((ushort4*)out)[off] = o;
}

// ================= QKV GEMM (two-phase): 128x384 tile, BK=64, 8 waves =================
// 256 blocks = 1/CU. XCD chunk = 8bm x 4grp, bm-fastest (round-12 best-measured mapping:
// FETCH 42MB, 60.4us). Ledger: B(t+1)@ph0(t), A(t+2)@ph1(t); vmcnt(2) keeps A(t+2) in flight.
__global__ __launch_bounds__(512, 2) void gemm_qkv384(const unsigned short* __restrict__ A,
                                                      const unsigned short* __restrict__ Bq,
                                                      const unsigned short* __restrict__ Bk,
                                                      const unsigned short* __restrict__ Bv,
                                                      unsigned short* __restrict__ Qo,
                                                      unsigned short* __restrict__ Ko,
                                                      unsigned short* __restrict__ Vt,
                                                      const float* __restrict__ ct,
                                                      const float* __restrict__ st) {
  __shared__ __align__(16) unsigned short Als[3][8192];      // 48KB
  __shared__ __align__(16) unsigned short Bls[3][2][8192];   // 96KB [bank][buf]
  const int tid = threadIdx.x, lane = tid & 63, wv = tid >> 6;
  const int wm = wv >> 2, wn = wv & 3;
  const int g = lane >> 4, r15 = lane & 15;
  // 256 blocks; XCD chunk = 8bm x 4grp, bm-fastest (B-panel L2-reuse across 8 blocks)
  const int c = blockIdx.x & 7, i = blockIdx.x >> 3;   // chunk, within
  const int bm = (c >> 1) * 8 + (i & 7);               // 0..31
  const int grp = (c & 1) * 4 + (i >> 3);              // 0..7 (3 bn-panels each)
  const int row0 = bm << 7;
  const unsigned short* Bpan[3];
  int bnp[3];
#pragma unroll
  for (int bk = 0; bk < 3; ++bk) {
    int p = grp * 3 + bk;
    bnp[bk] = p;
    Bpan[bk] = (p < 16) ? Bq + (size_t)(p << 7) * DMODEL
             : (p < 20) ? Bk + (size_t)((p - 16) << 7) * DMODEL
                        : Bv + (size_t)((p - 20) << 7) * DMODEL;
  }
  const int srow = tid >> 3;                             // 0..63
  const int scol = (((tid & 7) ^ ((tid >> 3) & 7)) << 3);
  const unsigned short* gA = A + (size_t)(row0 + srow) * DMODEL + scol;
  const unsigned short* gB0 = Bpan[0] + (size_t)srow * DMODEL + scol;
  const unsigned short* gB1 = Bpan[1] + (size_t)srow * DMODEL + scol;
  const unsigned short* gB2 = Bpan[2] + (size_t)srow * DMODEL + scol;

  f32x4 acc[4][6];
#pragma unroll
  for (int a = 0; a < 4; ++a)
#pragma unroll
    for (int b = 0; b < 6; ++b) acc[a][b] = (f32x4){0.f, 0.f, 0.f, 0.f};

#define STG_A(buf, kt) do { \
    gload16(gA + (size_t)(kt) * 64, &Als[buf][(wv << 9)]); \
    gload16(gA + (size_t)64 * DMODEL + (size_t)(kt) * 64, &Als[buf][4096 + (wv << 9)]); } while (0)
#define STG_B(bank, gp, buf, kt) do { \
    gload16(gp + (size_t)(kt) * 64, &Bls[bank][buf][(wv << 9)]); \
    gload16(gp + (size_t)64 * DMODEL + (size_t)(kt) * 64, &Bls[bank][buf][4096 + (wv << 9)]); } while (0)
#define RA(buf, mf, kk) (*(const bf16x8*)&Als[buf][((wm << 6) + ((mf) << 4) + r15) * 64 + \
                          (((((kk) << 2) + g) ^ (r15 & 7)) << 3)])
#define RB(bank, buf, sub, kk) (*(const bf16x8*)&Bls[bank][buf][((wn << 5) + ((sub) << 4) + r15) * 64 + \
                          (((((kk) << 2) + g) ^ (r15 & 7)) << 3)])

  STG_A(0, 0);
  STG_B(0, gB0, 0, 0); STG_B(1, gB1, 0, 0); STG_B(2, gB2, 0, 0);
  STG_A(1, 1);
  VMCNT(0);
  BARRIER();

  const int NT = DMODEL / 64;  // 32
  for (int t = 0; t < NT; ++t) {
    const int ab = t % 3, an2 = (t + 2) % 3;
    const int bb = t & 1, bn2 = bb ^ 1;
    // ---- ph0: read A(8) + banks 0,1 (8); stage B(t+1) x3; MFMA 32 ----
    bf16x8 af[4][2];
#pragma unroll
    for (int mf = 0; mf < 4; ++mf) { af[mf][0] = RA(ab, mf, 0); af[mf][1] = RA(ab, mf, 1); }
    bf16x8 b01[2][2][2];
#pragma unroll
    for (int bk = 0; bk < 2; ++bk)
#pragma unroll
      for (int sub = 0; sub < 2; ++sub) {
        b01[bk][sub][0] = RB(bk, bb, sub, 0);
        b01[bk][sub][1] = RB(bk, bb, sub, 1);
      }
    if (t + 1 < NT) {
      STG_B(0, gB0, bn2, t + 1); STG_B(1, gB1, bn2, t + 1); STG_B(2, gB2, bn2, t + 1);
    }
    BARRIER();
    __builtin_amdgcn_s_setprio(1);
#pragma unroll
    for (int mf = 0; mf < 4; ++mf)
#pragma unroll
      for (int bk = 0; bk < 2; ++bk)
#pragma unroll
        for (int sub = 0; sub < 2; ++sub) {
          acc[mf][bk * 2 + sub] = MFMA(af[mf][0], b01[bk][sub][0], acc[mf][bk * 2 + sub]);
          acc[mf][bk * 2 + sub] = MFMA(af[mf][1], b01[bk][sub][1], acc[mf][bk * 2 + sub]);
        }
    __builtin_amdgcn_s_setprio(0);
    BARRIER();
    // ---- ph1: read bank 2 (4); stage A(t+2); MFMA 16; counted drain ----
    bf16x8 b2[2][2];
#pragma unroll
    for (int sub = 0; sub < 2; ++sub) { b2[sub][0] = RB(2, bb, sub, 0); b2[sub][1] = RB(2, bb, sub, 1); }
    if (t + 2 < NT) STG_A(an2, t + 2);
    BARRIER();
    __builtin_amdgcn_s_setprio(1);
#pragma unroll
    for (int mf = 0; mf < 4; ++mf)
#pragma unroll
      for (int sub = 0; sub < 2; ++sub) {
        acc[mf][4 + sub] = MFMA(af[mf][0], b2[sub][0], acc[mf][4 + sub]);
        acc[mf][4 + sub] = MFMA(af[mf][1], b2[sub][1], acc[mf][4 + sub]);
      }
    __builtin_amdgcn_s_setprio(0);
    if (t + 2 < NT)      { VMCNT(2); }
    else if (t + 1 < NT) { VMCNT(0); }
    BARRIER();
  }
#undef STG_A
#undef STG_B
#undef RA
#undef RB

  // ---- epilogue: per-bank Q / K / V(transposed) ----
  const float QS = 0.18033688011112042f;  // 0.125 * log2(e)
#pragma unroll
  for (int bk = 0; bk < 3; ++bk) {
    const int p = bnp[bk];
    if (p < 20) {
      unsigned short* Outb = (p < 16) ? Qo : Ko;
      const int col0 = (p < 16) ? (p << 7) : ((p - 16) << 7);
      const int ldo = (p < 16) ? DMODEL : KVD;
      const int qsc = (p < 16);
#pragma unroll
      for (int mf = 0; mf < 4; ++mf) {
#pragma unroll
        for (int rr = 0; rr < 4; ++rr) {
          const int m = row0 + (wm << 6) + (mf << 4) + (g << 2) + rr;
          const float* ctr = ct + ((m & (SEQ - 1)) << 5);
          const float* str = st + ((m & (SEQ - 1)) << 5);
#pragma unroll
          for (int sub = 0; sub < 2; ++sub) {
            const int n = col0 + (wn << 5) + (sub << 4) + r15;
            float v = acc[mf][bk * 2 + sub][rr];
            float pv = __shfl_xor(v, 1);
            int fi = (n & 63) >> 1;
            float cc = ctr[fi], sn = str[fi];
            v = (lane & 1) ? (pv * sn + v * cc) : (v * cc - pv * sn);
            if (qsc) v *= QS;
            Outb[(size_t)m * ldo + n] = f2bf(v);
          }
        }
      }
    } else {
      const int col0 = (p - 20) << 7;
#pragma unroll
      for (int mf = 0; mf < 4; ++mf) {
        const int m0 = row0 + (wm << 6) + (mf << 4) + (g << 2);
        const int b = m0 >> 11, s0 = m0 & (SEQ - 1);
#pragma unroll
        for (int sub = 0; sub < 2; ++sub) {
          const int nv = col0 + (wn << 5) + (sub << 4) + r15;  // 0..511 = kvh*64+d
          ushort4 o;
          o.x = f2bf(acc[mf][bk * 2 + sub][0]);
          o.y = f2bf(acc[mf][bk * 2 + sub][1]);
          o.z = f2bf(acc[mf][bk * 2 + sub][2]);
          o.w = f2bf(acc[mf][bk * 2 + sub][3]);
          *(ushort4*)(Vt + ((size_t)(b * NKV * HDIM + nv)) * SEQ + s0) = o;
        }
      }
    }
  }
}

// ================= out-proj GEMM: 128x256, BK=64, 8 waves, SINGLE merged phase, 3-buf =================
__global__ __launch_bounds__(512) void gemm_out128(const unsigned short* __restrict__ A,
                                                   const unsigned short* __restrict__ B,
                                                   float* __restrict__ C) {
  __shared__ __align__(16) unsigned short Als[3][8192];      // [buf][128*64]
  __shared__ __align__(16) unsigned short Bls[3][2][8192];   // [buf][half][128*64]
  const int tid = threadIdx.x, lane = tid & 63, wv = tid >> 6;
  const int wm = wv >> 2, wn = wv & 3;
  const int g = lane >> 4, r15 = lane & 15;
  const int wgid = (blockIdx.x & 7) * 32 + (blockIdx.x >> 3);
  const int bm = wgid >> 3, bn = wgid & 7;
  const int row0 = bm << 7, col0 = bn << 8;
  const int srl = tid >> 3;
  const int sgc = ((tid & 7) ^ (srl & 7)) << 3;
  const unsigned short* gA = A + (size_t)(row0 + srl) * DMODEL + sgc;
  const unsigned short* gB = B + (size_t)(col0 + srl) * DMODEL + sgc;

  f32x4 acc[4][4];
#pragma unroll
  for (int i = 0; i < 4; ++i)
#pragma unroll
    for (int jj = 0; jj < 4; ++jj) acc[i][jj] = (f32x4){0.f, 0.f, 0.f, 0.f};

#define STG_A1(buf, kt) do { \
    gload16(gA + (size_t)(kt) * 64, &Als[buf][(wv << 9)]); \
    gload16(gA + (size_t)64 * DMODEL + (size_t)(kt) * 64, &Als[buf][4096 + (wv << 9)]); } while (0)
#define STG_B1(buf, h, kt) do { \
    gload16(gB + (size_t)((h) * 128) * DMODEL + (kt) * 64, &Bls[buf][h][(wv << 9)]); \
    gload16(gB + (size_t)((h) * 128 + 64) * DMODEL + (kt) * 64, &Bls[buf][h][4096 + (wv << 9)]); } while (0)
#define RA1(buf, mf, kk) (*(const bf16x8*)&Als[buf][((wm << 6) + (mf) * 16 + r15) * 64 + \
                           (((((kk) << 2) + g) ^ (r15 & 7)) << 3)])
#define RB1(buf, nf, kk) (*(const bf16x8*)&Bls[buf][wn >> 1][((wn & 1) * 64 + (nf) * 16 + r15) * 64 + \
                           (((((kk) << 2) + g) ^ (r15 & 7)) << 3)])

  STG_B1(0, 0, 0); STG_B1(0, 1, 0); STG_A1(0, 0);
  STG_B1(1, 0, 1); STG_B1(1, 1, 1); STG_A1(1, 1);
  VMCNT(6);
  BARRIER();

  const int NT = DMODEL / 64;  // 32
  for (int t = 0; t < NT; ++t) {
    const int cur = t % 3;
    const int stg = (t + 2) % 3;
    bf16x8 a[4][2], b0[2][2], b2[2][2];
#pragma unroll
    for (int mf = 0; mf < 4; ++mf) { a[mf][0] = RA1(cur, mf, 0); a[mf][1] = RA1(cur, mf, 1); }
#pragma unroll
    for (int nf = 0; nf < 2; ++nf) { b0[nf][0] = RB1(cur, nf, 0); b0[nf][1] = RB1(cur, nf, 1); }
#pragma unroll
    for (int nf = 0; nf < 2; ++nf) { b2[nf][0] = RB1(cur, 2 + nf, 0); b2[nf][1] = RB1(cur, 2 + nf, 1); }
    if (t + 2 < NT) { STG_B1(stg, 0, t + 2); STG_B1(stg, 1, t + 2); STG_A1(stg, t + 2); }
    BARRIER();
    __builtin_amdgcn_s_setprio(1);
#pragma unroll
    for (int mf = 0; mf < 4; ++mf)
#pragma unroll
      for (int nf = 0; nf < 2; ++nf) {
        acc[mf][nf] = MFMA(a[mf][0], b0[nf][0], acc[mf][nf]);
        acc[mf][nf] = MFMA(a[mf][1], b0[nf][1], acc[mf][nf]);
        acc[mf][2 + nf] = MFMA(a[mf][0], b2[nf][0], acc[mf][2 + nf]);
        acc[mf][2 + nf] = MFMA(a[mf][1], b2[nf][1], acc[mf][2 + nf]);
      }
    __builtin_amdgcn_s_setprio(0);
    if (t + 2 < NT) { VMCNT(6); }
    else if (t + 2 == NT) { VMCNT(0); }
    BARRIER();
  }
#undef STG_A1
#undef STG_B1
#undef RA1
#undef RB1

#pragma unroll
  for (int mf = 0; mf < 4; ++mf)
#pragma unroll
    for (int rr = 0; rr < 4; ++rr) {
      const int m = row0 + (wm << 6) + (mf) * 16 + (g << 2) + rr;
#pragma unroll
      for (int nf = 0; nf < 4; ++nf)
        C[(size_t)m * DMODEL + col0 + (wn << 6) + (nf << 4) + r15] = acc[mf][nf][rr];
    }
}

// ---------------- Flash attention: 8-wave, QBLK=128, KVBLK=128, 2-half T15 pipeline ----------------
__global__ __launch_bounds__(512, 4) void attn_fwd(const unsigned short* __restrict__ Q,
                                                   const unsigned short* __restrict__ K,
                                                   const unsigned short* __restrict__ Vt,
                                                   unsigned short* __restrict__ O) {
  __shared__ __align__(16) unsigned short Kls[2][2][64 * 64];
  __shared__ __align__(16) unsigned short Vls[2][2][64 * 64];
  const int bid = blockIdx.x;
  const int xcd = bid & 7;
  const int within = bid >> 3;             // 0..63
  const int grp = xcd * 2 + (within >> 5); // 0..15 = (b,kvh)
  const int w32 = within & 31;
  const int j = w32 & 7;                   // pair: q-tiles j and 15-j (128 rows each)
  const int hsub = w32 >> 3;
  const int b = grp >> 3, kvh = grp & 7;
  const int h = kvh * 4 + hsub;
  const int wave = threadIdx.x >> 6, lane = threadIdx.x & 63;  // 8 waves
  const int g = lane >> 4, r15 = lane & 15;
  const int sr = lane >> 3;
  const int sc = (((lane & 7) << 4) ^ (sr << 4)) >> 1;  // pre-swizzled src col (shorts)
  const unsigned short* kbase = K + (size_t)b * SEQ * KVD + kvh * HDIM;
  const unsigned short* vbase = Vt + (size_t)((b * NKV + kvh) * HDIM) * SEQ;

  union { u16x8 s; bf16x8 v; } one8;
#pragma unroll
  for (int z = 0; z < 8; ++z) one8.s[z] = 0x3F80;  // bf16 1.0

  auto STAGE = [&](int bi, int kbv) {
    const int r = wave * 8;   // 8 rows per wave per subtile
#pragma unroll
    for (int hh = 0; hh < 2; ++hh) {
      gload16(kbase + (size_t)(kbv + hh * 64 + r + sr) * KVD + sc, &Kls[bi][hh][r * 64]);
      gload16(vbase + (size_t)(r + sr) * SEQ + kbv + hh * 64 + sc, &Vls[bi][hh][r * 64]);
    }
  };

#pragma unroll 1
  for (int sel = 0; sel < 2; ++sel) {
    const int qt = sel ? (15 - j) : j;
    const int qrow0 = qt * 128 + wave * 16;
    const unsigned short* qp = Q + (size_t)(b * SEQ + qrow0 + r15) * DMODEL + h * HDIM;
    bf16x8 q0 = *(const bf16x8*)(qp + g * 8);
    bf16x8 q1 = *(const bf16x8*)(qp + 32 + g * 8);
    f32x4 oacc[4] = {};
    f32x4 lacc = {};
    const int kend = (qt + 1) * 128;
    __syncthreads();           // prior-tile reads drained before restaging
    STAGE(0, 0);
    int buf = 0;
    for (int kb = 0; kb < kend; kb += 128) {
      __syncthreads();         // staged loads for buf complete; buf^1 reads done
      if (kb + 128 < kend) STAGE(buf ^ 1, kb + 128);
      const char* Kc0 = (const char*)&Kls[buf][0][0];
      const char* Vc0 = (const char*)&Vls[buf][0][0];
      const char* Kc1 = (const char*)&Kls[buf][1][0];
      const char* Vc1 = (const char*)&Vls[buf][1][0];
      // ---- QK^T for BOTH halves first ----
      f32x4 s0[4], s1[4];
      __builtin_amdgcn_s_setprio(1);
#pragma unroll
      for (int f = 0; f < 4; ++f) {
        const int r = f * 16 + r15;
        const int sw = (r & 7) << 4;
        bf16x8 k0 = *(const bf16x8*)(Kc0 + r * 128 + ((g * 16) ^ sw));
        bf16x8 k1 = *(const bf16x8*)(Kc0 + r * 128 + ((64 + g * 16) ^ sw));
        f32x4 z = {};
        s0[f] = MFMA(k1, q1, MFMA(k0, q0, z));
      }
#pragma unroll
      for (int f = 0; f < 4; ++f) {
        const int r = f * 16 + r15;
        const int sw = (r & 7) << 4;
        bf16x8 k0 = *(const bf16x8*)(Kc1 + r * 128 + ((g * 16) ^ sw));
        bf16x8 k1 = *(const bf16x8*)(Kc1 + r * 128 + ((64 + g * 16) ^ sw));
        f32x4 z = {};
        s1[f] = MFMA(k1, q1, MFMA(k0, q0, z));
      }
      __builtin_amdgcn_s_setprio(0);
      // ---- softmax(h0) ----
      if (kb + 64 > qrow0) {
        const int q = qrow0 + r15;
#pragma unroll
        for (int f = 0; f < 4; ++f)
#pragma unroll
          for (int rr = 0; rr < 4; ++rr)
            if (kb + f * 16 + g * 4 + rr > q) s0[f][rr] = -1e30f;
      }
#pragma unroll
      for (int f = 0; f < 4; ++f)
#pragma unroll
        for (int rr = 0; rr < 4; ++rr) s0[f][rr] = exp2v(s0[f][rr]);
      bf16x8 p1a, p2a;
      {
        union { bf16x8 v; unsigned u[4]; } P1, P2;
        unsigned a0 = cvtpk(s0[0][0], s0[0][1]), b0 = cvtpk(s0[1][0], s0[1][1]);
        pl32(a0, b0); pl16(a0, b0);
        unsigned a1 = cvtpk(s0[0][2], s0[0][3]), b1 = cvtpk(s0[1][2], s0[1][3]);
        pl32(a1, b1); pl16(a1, b1);
        P1.u[0] = a0; P1.u[1] = a1; P1.u[2] = b0; P1.u[3] = b1;
        unsigned a2 = cvtpk(s0[2][0], s0[2][1]), b2 = cvtpk(s0[3][0], s0[3][1]);
        pl32(a2, b2); pl16(a2, b2);
        unsigned a3 = cvtpk(s0[2][2], s0[2][3]), b3 = cvtpk(s0[3][2], s0[3][3]);
        pl32(a3, b3); pl16(a3, b3);
        P2.u[0] = a2; P2.u[1] = a3; P2.u[2] = b2; P2.u[3] = b3;
        p1a = P1.v; p2a = P2.v;
      }
      lacc = MFMA(p2a, one8.v, MFMA(p1a, one8.v, lacc));
      // ---- PV(h0) ----
      __builtin_amdgcn_s_setprio(1);
#pragma unroll
      for (int dc = 0; dc < 4; ++dc) {
        const int r = dc * 16 + r15;
        const int sw = (r & 7) << 4;
        bf16x8 v0 = *(const bf16x8*)(Vc0 + r * 128 + ((g * 16) ^ sw));
        bf16x8 v1 = *(const bf16x8*)(Vc0 + r * 128 + ((64 + g * 16) ^ sw));
        oacc[dc] = MFMA(p2a, v1, MFMA(p1a, v0, oacc[dc]));
      }
      __builtin_amdgcn_s_setprio(0);
      // ---- softmax(h1) (overlaps PV(h0)) ----
      const int cb1 = kb + 64;
      if (cb1 + 64 > qrow0) {
        const int q = qrow0 + r15;
#pragma unroll
        for (int f = 0; f < 4; ++f)
#pragma unroll
          for (int rr = 0; rr < 4; ++rr)
            if (cb1 + f * 16 + g * 4 + rr > q) s1[f][rr] = -1e30f;
      }
#pragma unroll
      for (int f = 0; f < 4; ++f)
#pragma unroll
        for (int rr = 0; rr < 4; ++rr) s1[f][rr] = exp2v(s1[f][rr]);
      bf16x8 p1b, p2b;
      {
        union { bf16x8 v; unsigned u[4]; } P1, P2;
        unsigned a0 = cvtpk(s1[0][0], s1[0][1]), b0 = cvtpk(s1[1][0], s1[1][1]);
        pl32(a0, b0); pl16(a0, b0);
        unsigned a1 = cvtpk(s1[0][2], s1[0][3]), b1 = cvtpk(s1[1][2], s1[1][3]);
        pl32(a1, b1); pl16(a1, b1);
        P1.u[0] = a0; P1.u[1] = a1; P1.u[2] = b0; P1.u[3] = b1;
        unsigned a2 = cvtpk(s1[2][0], s1[2][1]), b2 = cvtpk(s1[3][0], s1[3][1]);
        pl32(a2, b2); pl16(a2, b2);
        unsigned a3 = cvtpk(s1[2][2], s1[2][3]), b3 = cvtpk(s1[3][2], s1[3][3]);
        pl32(a3, b3); pl16(a3, b3);
        P2.u[0] = a2; P2.u[1] = a3; P2.u[2] = b2; P2.u[3] = b3;
        p1b = P1.v; p2b = P2.v;
      }
      lacc = MFMA(p2b, one8.v, MFMA(p1b, one8.v, lacc));
      // ---- PV(h1) ----
      __builtin_amdgcn_s_setprio(1);
#pragma unroll
      for (int dc = 0; dc < 4; ++dc) {
        const int r = dc * 16 + r15;
        const int sw = (r & 7) << 4;
        bf16x8 v0 = *(const bf16x8*)(Vc1 + r * 128 + ((g * 16) ^ sw));
        bf16x8 v1 = *(const bf16x8*)(Vc1 + r * 128 + ((64 + g * 16) ^ sw));
        oacc[dc] = MFMA(p2b, v1, MFMA(p1b, v0, oacc[dc]));
      }
      __builtin_amdgcn_s_setprio(0);
      buf ^= 1;
    }
    float rls[4];
#pragma unroll
    for (int rr = 0; rr < 4; ++rr) rls[rr] = 1.0f / lacc[rr];
    unsigned short* optr = O + (size_t)(b * SEQ + qrow0) * DMODEL + h * HDIM;
#pragma unroll
    for (int dc = 0; dc < 4; ++dc)
#pragma unroll
      for (int rr = 0; rr < 4; ++rr)
        optr[(size_t)(g * 4 + rr) * DMODEL + dc * 16 + r15] = f2bf(oacc[dc][rr] * rls[rr]);
  }
}

extern "C" void kernel_launch(void* const* d_in, const int* in_sizes, int n_in,
                              void* d_out, int out_size, void* d_ws, size_t ws_size,
                              hipStream_t stream) {
  const float* x  = (const float*)d_in[0];
  const float* Wq = (const float*)d_in[1];
  const float* Wk = (const float*)d_in[2];
  const float* Wv = (const float*)d_in[3];
  const float* Wo = (const float*)d_in[4];

  char* ws = (char*)d_ws;
  unsigned short* xb  = (unsigned short*)(ws);                    // 16 MiB
  unsigned short* Wqb = (unsigned short*)(ws + (16u << 20));      // 8 MiB
  unsigned short* Wkb = (unsigned short*)(ws + (24u << 20));      // 2 MiB
  unsigned short* Wvb = (unsigned short*)(ws + (26u << 20));      // 2 MiB
  unsigned short* Wob = (unsigned short*)(ws + (28u << 20));      // 8 MiB
  unsigned short* Qb  = (unsigned short*)(ws + (36u << 20));      // 16 MiB
  unsigned short* Kb  = (unsigned short*)(ws + (52u << 20));      // 4 MiB
  unsigned short* Vtb = (unsigned short*)(ws + (60u << 20));      // 4 MiB
  unsigned short* AO  = (unsigned short*)(ws + (64u << 20));      // 16 MiB
  float* ct = (float*)(ws + (80u << 20));                         // 256 KiB
  float* st = (float*)(ws + (81u << 20));                         // 256 KiB

  conv_all<<<18688, 256, 0, stream>>>(x, Wq, Wk, Wv, Wo, xb, Wqb, Wkb, Wvb, Wob, ct, st);

  gemm_qkv384<<<256, 512, 0, stream>>>(xb, Wqb, Wkb, Wvb, Qb, Kb, Vtb, ct, st);

  attn_fwd<<<512, 512, 0, stream>>>(Qb, Kb, Vtb, AO);

  gemm_out128<<<256, 512, 0, stream>>>(AO, Wob, (float*)d_out);
}